// Round 9
// baseline (218.939 us; speedup 1.0000x reference)
//
#include <hip/hip_runtime.h>
#include <hip/hip_fp16.h>

#define B_ 4
#define T_ 4096
#define D_ 1024

typedef _Float16 h8 __attribute__((ext_vector_type(8)));
typedef _Float16 h4 __attribute__((ext_vector_type(4)));
typedef float f32x4 __attribute__((ext_vector_type(4)));

#define LOG2E 1.44269504088896340736f
#define MASKV -3.0e38f
#define MINIT -1.0e30f
#define EXP2(x) __builtin_amdgcn_exp2f(x)

// ---------------- kernel 0: W (1024x192 f32) -> Wt (192x1024 f16), LDS transpose
__global__ __launch_bounds__(256) void wt_kernel(const float* __restrict__ W,
                                                 _Float16* __restrict__ Wt) {
    __shared__ _Float16 Tr[192][20];
    const int tid = threadIdx.x, k0 = blockIdx.x * 16;   // grid 64
#pragma unroll
    for (int i = 0; i < 3; i++) {
        int fi = tid + 256 * i;                 // 768 float4 = 16 rows x 48
        int r = fi / 48, c4 = fi % 48;
        float4 v = *(const float4*)(W + (size_t)(k0 + r) * 192 + c4 * 4);
        Tr[c4 * 4 + 0][r] = (_Float16)v.x;
        Tr[c4 * 4 + 1][r] = (_Float16)v.y;
        Tr[c4 * 4 + 2][r] = (_Float16)v.z;
        Tr[c4 * 4 + 3][r] = (_Float16)v.w;
    }
    __syncthreads();
#pragma unroll
    for (int i = 0; i < 3; i++) {
        int oi = tid + 256 * i;                 // 768 h4 = 192 rows x 4
        int n = oi >> 2, kq = oi & 3;
        *(h4*)(Wt + (size_t)n * D_ + k0 + kq * 4) = *(const h4*)&Tr[n][kq * 4];
    }
}

// ---------------- kernel 1: qkv projection, BM=32 BN=192 BK=32, dbuf LDS, grid 512
// Ost epilogue staging overlaid on As/Bs -> 35.8 KB LDS -> 4 blocks/CU.
__global__ __launch_bounds__(256) void proj_kernel(
    const float* __restrict__ x, const _Float16* __restrict__ Wt,
    const float* __restrict__ bias,
    _Float16* __restrict__ qh, _Float16* __restrict__ kh, _Float16* __restrict__ vh)
{
    __shared__ __align__(16) char psm[35840];
    _Float16* Asp = (_Float16*)psm;             // [2][32][40]
    _Float16* Bsp = (_Float16*)(psm + 5120);    // [2][192][40]
    _Float16* Ostp = (_Float16*)psm;            // [32][200] (aliases As/Bs, used after)
    const int tid = threadIdx.x;
    const int w = tid >> 6, lane = tid & 63, quad = lane >> 4, l16 = lane & 15;
    const int row0 = blockIdx.x * 32;
    const int mstrip = w & 1;
    const int ngrp = (w >> 1) * 6;

    float bvals[6];
#pragma unroll
    for (int nt = 0; nt < 6; nt++) bvals[nt] = bias[(ngrp + nt) * 16 + l16];

    f32x4 acc[6];
#pragma unroll
    for (int i = 0; i < 6; i++) acc[i] = (f32x4){0.f, 0.f, 0.f, 0.f};

    const int arow = tid >> 3, ac0 = (tid & 7) * 4;

    float4 xa;
    h8 wreg[3];
    {
        xa = *(const float4*)(x + (size_t)(row0 + arow) * D_ + ac0);
#pragma unroll
        for (int p = 0; p < 3; p++) {
            int f = tid + 256 * p; int n = f >> 2, c0 = (f & 3) * 8;
            wreg[p] = *(const h8*)(Wt + (size_t)n * D_ + c0);
        }
    }

    for (int kc = 0; kc < 32; kc++) {
        const int buf = kc & 1;
        h4 av;
        av[0]=(_Float16)xa.x; av[1]=(_Float16)xa.y; av[2]=(_Float16)xa.z; av[3]=(_Float16)xa.w;
        *(h4*)(Asp + buf * 1280 + arow * 40 + ac0) = av;
#pragma unroll
        for (int p = 0; p < 3; p++) {
            int f = tid + 256 * p; int n = f >> 2, c0 = (f & 3) * 8;
            *(h8*)(Bsp + buf * 7680 + n * 40 + c0) = wreg[p];
        }
        if (kc + 1 < 32) {
            int k0 = (kc + 1) * 32;
            xa = *(const float4*)(x + (size_t)(row0 + arow) * D_ + k0 + ac0);
#pragma unroll
            for (int p = 0; p < 3; p++) {
                int f = tid + 256 * p; int n = f >> 2, c0 = (f & 3) * 8;
                wreg[p] = *(const h8*)(Wt + (size_t)n * D_ + k0 + c0);
            }
        }
        __syncthreads();
        h8 a0 = *(const h8*)(Asp + buf * 1280 + (16 * mstrip + l16) * 40 + quad * 8);
#pragma unroll
        for (int nt = 0; nt < 6; nt++) {
            h8 b0 = *(const h8*)(Bsp + buf * 7680 + ((ngrp + nt) * 16 + l16) * 40 + quad * 8);
            acc[nt] = __builtin_amdgcn_mfma_f32_16x16x32_f16(a0, b0, acc[nt], 0, 0, 0);
        }
    }

    __syncthreads();   // all waves done with As/Bs before Ost overlay
#pragma unroll
    for (int nt = 0; nt < 6; nt++) {
        int n = (ngrp + nt) * 16 + l16;
        float scale = (n < 64) ? LOG2E : 1.0f;   // q pre-scaled for exp2 softmax
#pragma unroll
        for (int reg = 0; reg < 4; reg++)
            Ostp[(16 * mstrip + quad * 4 + reg) * 200 + n] =
                (_Float16)((acc[nt][reg] + bvals[nt]) * scale);
    }
    __syncthreads();
    {
        const int mrow = tid >> 3, c0 = (tid & 7) * 8;
        _Float16* dsts[3] = {qh, kh, vh};
#pragma unroll
        for (int g = 0; g < 3; g++)
            *(h8*)(dsts[g] + (size_t)(row0 + mrow) * 64 + c0) =
                *(const h8*)(Ostp + mrow * 200 + g * 64 + c0);
    }
}

// ---------------- kernel 2: flash attention chunks; 128-row q-tile (2 strips/wave),
// K direct-from-global fragments (no Ks LDS), V dbuf LDS, transposed-S, XCD-clustered.
__global__ __launch_bounds__(256, 4) void attn_kernel(
    const _Float16* __restrict__ qh, const _Float16* __restrict__ kh,
    const _Float16* __restrict__ vh, float* __restrict__ out,
    _Float16* __restrict__ Opart, float2* __restrict__ ml,
    int lgC, int NC1, int direct, int q8, int total)
{
    __shared__ _Float16 Vt[2][64][72];   // [buf][p][s]; reused as 128x72 O-staging
    const int tid = threadIdx.x;
    const int w = tid >> 6, lane = tid & 63, quad = lane >> 4, l16 = lane & 15;
    const int C = 1 << lgC;

    const int bid = blockIdx.x;
    const int cid = (bid & 7) * q8 + (bid >> 3);   // XCD clustering
    if (cid >= total) return;

    const int b = cid / NC1;
    int rem = cid - b * NC1;
    int qt2 = 0, k0 = 0, cnt = 1;
    for (int i = 0; i < 32; i++) {
        int nc = (2 * i + 2 + C - 1) >> lgC;
        if (rem < nc) { qt2 = i; k0 = rem << lgC; cnt = min(C, 2 * i + 2 - k0); break; }
        rem -= nc;
    }
    const size_t base = (size_t)b * T_ * 64;
    const int qbase = qt2 * 128 + w * 32;   // wave's first q-row

    // Q fragments for 2 strips
    h8 qf[2][2];
#pragma unroll
    for (int u = 0; u < 2; u++) {
        const _Float16* qp = qh + base + (size_t)(qbase + u * 16 + l16) * 64 + quad * 8;
        qf[u][0] = *(const h8*)qp;
        qf[u][1] = *(const h8*)(qp + 32);
    }

    f32x4 o[8];   // O^T tiles, C-layout: row=p(quad*4+reg), col=m(l16)
#pragma unroll
    for (int i = 0; i < 8; i++) o[i] = (f32x4){0.f, 0.f, 0.f, 0.f};
    float m[2] = {MINIT, MINIT}, l[2] = {0.f, 0.f};

    // V staging regs (coalesced), transposed into Vt each iter
    const int vp0 = (tid & 15) * 4, vc0 = (tid >> 4) * 4;
    h4 vreg[4];
    {
        const _Float16* vp = vh + base + (size_t)(k0 * 64 + vc0) * 64 + vp0;
#pragma unroll
        for (int i = 0; i < 4; i++) vreg[i] = *(const h4*)(vp + (size_t)i * 64);
    }

    // K fragments direct from global (rows s = nt*16+l16, cols d = quad*8+j)
    const _Float16* kbase = kh + base + (size_t)l16 * 64 + quad * 8;
    h8 kf[4][2];
    {
        const _Float16* kp = kbase + (size_t)k0 * 4096;
#pragma unroll
        for (int nt = 0; nt < 4; nt++) {
            kf[nt][0] = *(const h8*)(kp + (size_t)nt * 1024);
            kf[nt][1] = *(const h8*)(kp + (size_t)nt * 1024 + 32);
        }
    }

    const int kend = k0 + cnt;
    for (int kt = k0; kt < kend; kt++) {
        const int buf = kt & 1;
#pragma unroll
        for (int j = 0; j < 4; j++) {
            h4 t;
            t[0] = vreg[0][j]; t[1] = vreg[1][j]; t[2] = vreg[2][j]; t[3] = vreg[3][j];
            *(h4*)&Vt[buf][vp0 + j][vc0] = t;
        }
        if (kt + 1 < kend) {   // prefetch next V tile
            const _Float16* vp = vh + base + (size_t)((kt + 1) * 64 + vc0) * 64 + vp0;
#pragma unroll
            for (int i = 0; i < 4; i++) vreg[i] = *(const h4*)(vp + (size_t)i * 64);
        }
        __syncthreads();

        const bool skip = (kt * 64) > (qbase + 31);   // wave fully above diagonal
        if (!skip) {
            h4 pf[2][4];
#pragma unroll
            for (int u = 0; u < 2; u++) {
                // S^T strip u: D[s=quad*4+reg][m=l16]
                f32x4 s[4];
#pragma unroll
                for (int nt = 0; nt < 4; nt++) {
                    f32x4 c = (f32x4){0.f, 0.f, 0.f, 0.f};
                    c = __builtin_amdgcn_mfma_f32_16x16x32_f16(kf[nt][0], qf[u][0], c, 0, 0, 0);
                    c = __builtin_amdgcn_mfma_f32_16x16x32_f16(kf[nt][1], qf[u][1], c, 0, 0, 0);
                    s[nt] = c;
                }
                const int qrow = qbase + u * 16 + l16;
                if (kt * 64 + 63 > qbase + u * 16) {   // causal mask needed
#pragma unroll
                    for (int nt = 0; nt < 4; nt++)
#pragma unroll
                        for (int reg = 0; reg < 4; reg++) {
                            int sg = kt * 64 + nt * 16 + quad * 4 + reg;
                            if (sg > qrow) s[nt][reg] = MASKV;
                        }
                }
                float mx = s[0][0];
#pragma unroll
                for (int nt = 0; nt < 4; nt++)
#pragma unroll
                    for (int reg = 0; reg < 4; reg++) mx = fmaxf(mx, s[nt][reg]);
                mx = fmaxf(mx, __shfl_xor(mx, 16));
                mx = fmaxf(mx, __shfl_xor(mx, 32));
                float mnew = fmaxf(m[u], mx);
                float alpha = EXP2(m[u] - mnew);
                m[u] = mnew;
                float rs = 0.f;
#pragma unroll
                for (int nt = 0; nt < 4; nt++) {
                    h4 ph;
#pragma unroll
                    for (int reg = 0; reg < 4; reg++) {
                        float p = EXP2(s[nt][reg] - mnew);
                        rs += p;
                        ph[reg] = (_Float16)p;
                    }
                    pf[u][nt] = ph;
                }
                rs += __shfl_xor(rs, 16);
                rs += __shfl_xor(rs, 32);
                l[u] = l[u] * alpha + rs;
#pragma unroll
                for (int pt = 0; pt < 4; pt++)
#pragma unroll
                    for (int reg = 0; reg < 4; reg++) o[u * 4 + pt][reg] *= alpha;
            }

            // kf consumed by both strips -> prefetch next K tile under PV
            if (kt + 1 < kend) {
                const _Float16* kp = kbase + (size_t)(kt + 1) * 4096;
#pragma unroll
                for (int nt = 0; nt < 4; nt++) {
                    kf[nt][0] = *(const h8*)(kp + (size_t)nt * 1024);
                    kf[nt][1] = *(const h8*)(kp + (size_t)nt * 1024 + 32);
                }
            }

            // O^T += V^T P^T ; vf shared across strips
#pragma unroll
            for (int pt = 0; pt < 4; pt++)
#pragma unroll
                for (int nt = 0; nt < 4; nt++) {
                    h4 vf = *(const h4*)&Vt[buf][pt * 16 + l16][nt * 16 + quad * 4];
                    o[pt]     = __builtin_amdgcn_mfma_f32_16x16x16f16(vf, pf[0][nt], o[pt], 0, 0, 0);
                    o[4 + pt] = __builtin_amdgcn_mfma_f32_16x16x16f16(vf, pf[1][nt], o[4 + pt], 0, 0, 0);
                }
        } else if (kt + 1 < kend) {   // keep prefetch alive on skipped iters
            const _Float16* kp = kbase + (size_t)(kt + 1) * 4096;
#pragma unroll
            for (int nt = 0; nt < 4; nt++) {
                kf[nt][0] = *(const h8*)(kp + (size_t)nt * 1024);
                kf[nt][1] = *(const h8*)(kp + (size_t)nt * 1024 + 32);
            }
        }
    }

    if (direct) {
#pragma unroll
        for (int u = 0; u < 2; u++) {
            float linv = 1.0f / l[u];
            int trow = qt2 * 128 + w * 32 + u * 16 + l16;
#pragma unroll
            for (int pt = 0; pt < 4; pt++)
#pragma unroll
                for (int reg = 0; reg < 4; reg++)
                    out[base + (size_t)trow * 64 + pt * 16 + quad * 4 + reg] =
                        o[u * 4 + pt][reg] * linv;
        }
    } else {
        // stage O^T -> LDS -> coalesced h8 stores
        __syncthreads();                       // all waves done reading Vt
        _Float16* St = &Vt[0][0][0];           // 128 x 72 halfs (exactly 9216)
#pragma unroll
        for (int u = 0; u < 2; u++) {
            int r = w * 32 + u * 16 + l16;
#pragma unroll
            for (int pt = 0; pt < 4; pt++) {
                h4 ph;
#pragma unroll
                for (int reg = 0; reg < 4; reg++) ph[reg] = (_Float16)o[u * 4 + pt][reg];
                *(h4*)&St[r * 72 + pt * 16 + quad * 4] = ph;
            }
            if (quad == 0) ml[(size_t)cid * 128 + r] = make_float2(m[u], l[u]);
        }
        __syncthreads();
        _Float16* op = Opart + (size_t)cid * 8192;   // [128][64] f16
        const int r = tid >> 1, c0 = (tid & 1) * 32;
#pragma unroll
        for (int j = 0; j < 4; j++)
            *(h8*)(op + r * 64 + c0 + 8 * j) = *(const h8*)&St[r * 72 + c0 + 8 * j];
    }
}

// ---------------- kernel 3: merge split-K partials; grid 1024 (16-row groups)
__global__ __launch_bounds__(256) void combine_kernel(
    const _Float16* __restrict__ Opart, const float2* __restrict__ ml,
    float* __restrict__ out, int lgC, int NC1)
{
    const int C = 1 << lgC;
    const int task = blockIdx.x;                  // b(2b) | tile(5b) | rg(3b)
    const int b = task >> 8, tile = (task >> 3) & 31, rg = task & 7;
    int pref = 0;
    for (int i = 0; i < tile; i++) pref += (2 * i + 2 + C - 1) >> lgC;
    const int cbase = b * NC1 + pref;
    const int nch = (2 * tile + 2 + C - 1) >> lgC;

    const int r = rg * 16 + (threadIdx.x >> 4);   // local row in [0,128)
    const int c0 = (threadIdx.x & 15) * 4;

    float M = MINIT;
    for (int i = 0; i < nch; i++) M = fmaxf(M, ml[(size_t)(cbase + i) * 128 + r].x);
    float L = 0.f, acc[4] = {0.f, 0.f, 0.f, 0.f};
    for (int i = 0; i < nch; i++) {
        float2 v = ml[(size_t)(cbase + i) * 128 + r];
        float sc = EXP2(v.x - M);
        L += sc * v.y;
        h4 x4 = *(const h4*)(Opart + (size_t)(cbase + i) * 8192 + (size_t)r * 64 + c0);
#pragma unroll
        for (int t = 0; t < 4; t++) acc[t] += sc * (float)x4[t];
    }
    float inv = 1.0f / L;
    float4 res = { acc[0]*inv, acc[1]*inv, acc[2]*inv, acc[3]*inv };
    *(float4*)(out + ((size_t)b * T_ + tile * 128 + r) * 64 + c0) = res;
}

extern "C" void kernel_launch(void* const* d_in, const int* in_sizes, int n_in,
                              void* d_out, int out_size, void* d_ws, size_t ws_size,
                              hipStream_t stream) {
    const float* x    = (const float*)d_in[0];
    const float* W    = (const float*)d_in[1];
    const float* bias = (const float*)d_in[2];
    float* out = (float*)d_out;
    char* ws = (char*)d_ws;
    _Float16* qh = (_Float16*)(ws);
    _Float16* kh = (_Float16*)(ws + (size_t)2 * 1024 * 1024);
    _Float16* vh = (_Float16*)(ws + (size_t)4 * 1024 * 1024);
    _Float16* Wt = (_Float16*)(ws + (size_t)6 * 1024 * 1024);
    const size_t pbase = (size_t)8 * 1024 * 1024;

    // smallest C whose f16 partials fit in ws (128-row tiles)
    int lgC = -1, nc1 = 32;
    for (int lg = 2; lg <= 6; lg++) {
        int C = 1 << lg, n1 = 0;
        for (int i = 0; i < 32; i++) n1 += (2 * i + 2 + C - 1) >> lg;
        size_t need = pbase + (size_t)4 * n1 * (8192 * 2 + 128 * 8);
        if (need <= ws_size) { lgC = lg; nc1 = n1; break; }
    }
    int direct = (lgC < 0) ? 1 : 0;
    if (direct) { lgC = 6; nc1 = 32; }
    _Float16* Opart = (_Float16*)(ws + pbase);
    float2*   mlp   = (float2*)(ws + pbase + (size_t)4 * nc1 * 8192 * 2);

    const int total = 4 * nc1;
    const int q8 = (total + 7) / 8;

    wt_kernel<<<64, 256, 0, stream>>>(W, Wt);
    proj_kernel<<<512, 256, 0, stream>>>(x, Wt, bias, qh, kh, vh);
    attn_kernel<<<8 * q8, 256, 0, stream>>>(qh, kh, vh, out, Opart, mlp,
                                            lgC, nc1, direct, q8, total);
    if (!direct)
        combine_kernel<<<1024, 256, 0, stream>>>(Opart, mlp, out, lgC, nc1);
}

// Round 10
// 155.537 us; speedup vs baseline: 1.4076x; 1.4076x over previous
//
#include <hip/hip_runtime.h>
#include <hip/hip_fp16.h>

#define B_ 4
#define T_ 4096
#define D_ 1024

typedef _Float16 h8 __attribute__((ext_vector_type(8)));
typedef _Float16 h4 __attribute__((ext_vector_type(4)));
typedef float f32x4 __attribute__((ext_vector_type(4)));

#define LOG2E 1.44269504088896340736f
#define MASKV -3.0e38f
#define MINIT -1.0e30f
#define EXP2(x) __builtin_amdgcn_exp2f(x)

// ---------------- kernel 0: W (1024x192 f32) -> Wt (192x1024 f16), LDS transpose
__global__ __launch_bounds__(256) void wt_kernel(const float* __restrict__ W,
                                                 _Float16* __restrict__ Wt) {
    __shared__ _Float16 Tr[192][20];
    const int tid = threadIdx.x, k0 = blockIdx.x * 16;   // grid 64
#pragma unroll
    for (int i = 0; i < 3; i++) {
        int fi = tid + 256 * i;                 // 768 float4 = 16 rows x 48
        int r = fi / 48, c4 = fi % 48;
        float4 v = *(const float4*)(W + (size_t)(k0 + r) * 192 + c4 * 4);
        Tr[c4 * 4 + 0][r] = (_Float16)v.x;
        Tr[c4 * 4 + 1][r] = (_Float16)v.y;
        Tr[c4 * 4 + 2][r] = (_Float16)v.z;
        Tr[c4 * 4 + 3][r] = (_Float16)v.w;
    }
    __syncthreads();
#pragma unroll
    for (int i = 0; i < 3; i++) {
        int oi = tid + 256 * i;                 // 768 h4 = 192 rows x 4
        int n = oi >> 2, kq = oi & 3;
        *(h4*)(Wt + (size_t)n * D_ + k0 + kq * 4) = *(const h4*)&Tr[n][kq * 4];
    }
}

// ---------------- kernel 1: qkv projection, BM=32 BN=192 BK=32, dbuf LDS, grid 512
// Ost epilogue staging overlaid on As/Bs -> 35.8 KB LDS -> 4 blocks/CU.
__global__ __launch_bounds__(256) void proj_kernel(
    const float* __restrict__ x, const _Float16* __restrict__ Wt,
    const float* __restrict__ bias,
    _Float16* __restrict__ qh, _Float16* __restrict__ kh, _Float16* __restrict__ vh)
{
    __shared__ __align__(16) char psm[35840];
    _Float16* Asp = (_Float16*)psm;             // [2][32][40]
    _Float16* Bsp = (_Float16*)(psm + 5120);    // [2][192][40]
    _Float16* Ostp = (_Float16*)psm;            // [32][200] (aliases As/Bs, used after)
    const int tid = threadIdx.x;
    const int w = tid >> 6, lane = tid & 63, quad = lane >> 4, l16 = lane & 15;
    const int row0 = blockIdx.x * 32;
    const int mstrip = w & 1;
    const int ngrp = (w >> 1) * 6;

    float bvals[6];
#pragma unroll
    for (int nt = 0; nt < 6; nt++) bvals[nt] = bias[(ngrp + nt) * 16 + l16];

    f32x4 acc[6];
#pragma unroll
    for (int i = 0; i < 6; i++) acc[i] = (f32x4){0.f, 0.f, 0.f, 0.f};

    const int arow = tid >> 3, ac0 = (tid & 7) * 4;

    float4 xa;
    h8 wreg[3];
    {
        xa = *(const float4*)(x + (size_t)(row0 + arow) * D_ + ac0);
#pragma unroll
        for (int p = 0; p < 3; p++) {
            int f = tid + 256 * p; int n = f >> 2, c0 = (f & 3) * 8;
            wreg[p] = *(const h8*)(Wt + (size_t)n * D_ + c0);
        }
    }

    for (int kc = 0; kc < 32; kc++) {
        const int buf = kc & 1;
        h4 av;
        av[0]=(_Float16)xa.x; av[1]=(_Float16)xa.y; av[2]=(_Float16)xa.z; av[3]=(_Float16)xa.w;
        *(h4*)(Asp + buf * 1280 + arow * 40 + ac0) = av;
#pragma unroll
        for (int p = 0; p < 3; p++) {
            int f = tid + 256 * p; int n = f >> 2, c0 = (f & 3) * 8;
            *(h8*)(Bsp + buf * 7680 + n * 40 + c0) = wreg[p];
        }
        if (kc + 1 < 32) {
            int k0 = (kc + 1) * 32;
            xa = *(const float4*)(x + (size_t)(row0 + arow) * D_ + k0 + ac0);
#pragma unroll
            for (int p = 0; p < 3; p++) {
                int f = tid + 256 * p; int n = f >> 2, c0 = (f & 3) * 8;
                wreg[p] = *(const h8*)(Wt + (size_t)n * D_ + k0 + c0);
            }
        }
        __syncthreads();
        h8 a0 = *(const h8*)(Asp + buf * 1280 + (16 * mstrip + l16) * 40 + quad * 8);
#pragma unroll
        for (int nt = 0; nt < 6; nt++) {
            h8 b0 = *(const h8*)(Bsp + buf * 7680 + ((ngrp + nt) * 16 + l16) * 40 + quad * 8);
            acc[nt] = __builtin_amdgcn_mfma_f32_16x16x32_f16(a0, b0, acc[nt], 0, 0, 0);
        }
    }

    __syncthreads();   // all waves done with As/Bs before Ost overlay
#pragma unroll
    for (int nt = 0; nt < 6; nt++) {
        int n = (ngrp + nt) * 16 + l16;
        float scale = (n < 64) ? LOG2E : 1.0f;   // q pre-scaled for exp2 softmax
#pragma unroll
        for (int reg = 0; reg < 4; reg++)
            Ostp[(16 * mstrip + quad * 4 + reg) * 200 + n] =
                (_Float16)((acc[nt][reg] + bvals[nt]) * scale);
    }
    __syncthreads();
    {
        const int mrow = tid >> 3, c0 = (tid & 7) * 8;
        _Float16* dsts[3] = {qh, kh, vh};
#pragma unroll
        for (int g = 0; g < 3; g++)
            *(h8*)(dsts[g] + (size_t)(row0 + mrow) * 64 + c0) =
                *(const h8*)(Ostp + mrow * 200 + g * 64 + c0);
    }
}

// ---------------- kernel 2: flash attention chunks; 128-row q-tile (2 strips/wave),
// K+V dbuf in LDS, transposed-S, XCD-clustered. launch_bounds(256,2): no VGPR spill.
__global__ __launch_bounds__(256, 2) void attn_kernel(
    const _Float16* __restrict__ qh, const _Float16* __restrict__ kh,
    const _Float16* __restrict__ vh, float* __restrict__ out,
    _Float16* __restrict__ Opart, float2* __restrict__ ml,
    int lgC, int NC1, int direct, int q8, int total)
{
    __shared__ _Float16 Ks[2][64][72];   // [buf][s][d]; reused as 128x72 O-staging
    __shared__ _Float16 Vt[2][64][72];   // [buf][p][s]
    const int tid = threadIdx.x;
    const int w = tid >> 6, lane = tid & 63, quad = lane >> 4, l16 = lane & 15;
    const int C = 1 << lgC;

    const int bid = blockIdx.x;
    const int cid = (bid & 7) * q8 + (bid >> 3);   // XCD clustering
    if (cid >= total) return;

    const int b = cid / NC1;
    int rem = cid - b * NC1;
    int qt2 = 0, k0 = 0, cnt = 1;
    for (int i = 0; i < 32; i++) {
        int nc = (2 * i + 2 + C - 1) >> lgC;
        if (rem < nc) { qt2 = i; k0 = rem << lgC; cnt = min(C, 2 * i + 2 - k0); break; }
        rem -= nc;
    }
    const size_t base = (size_t)b * T_ * 64;
    const int qbase = qt2 * 128 + w * 32;   // wave's first q-row

    // Q fragments for 2 strips (A/B layout: [l16][quad*8+j])
    h8 qf[2][2];
#pragma unroll
    for (int u = 0; u < 2; u++) {
        const _Float16* qp = qh + base + (size_t)(qbase + u * 16 + l16) * 64 + quad * 8;
        qf[u][0] = *(const h8*)qp;
        qf[u][1] = *(const h8*)(qp + 32);
    }

    f32x4 o[8];   // O^T tiles, C-layout: row=p(quad*4+reg), col=m(l16)
#pragma unroll
    for (int i = 0; i < 8; i++) o[i] = (f32x4){0.f, 0.f, 0.f, 0.f};
    float m[2] = {MINIT, MINIT}, l[2] = {0.f, 0.f};

    // staging maps
    const int krow = tid >> 3, kc0 = (tid & 7) * 8;          // K: 2 x h8 per thread
    const int vp0 = (tid & 15) * 4, vc0 = (tid >> 4) * 4;    // V: 4 x h4, reg transpose
    h8 kreg[2];
    h4 vreg[4];
    {
        const _Float16* kp = kh + base + (size_t)(k0 * 64) * 64;
        kreg[0] = *(const h8*)(kp + (size_t)krow * 64 + kc0);
        kreg[1] = *(const h8*)(kp + (size_t)(krow + 32) * 64 + kc0);
        const _Float16* vp = vh + base + (size_t)(k0 * 64 + vc0) * 64 + vp0;
#pragma unroll
        for (int i = 0; i < 4; i++) vreg[i] = *(const h4*)(vp + (size_t)i * 64);
    }

    const int kend = k0 + cnt;
    for (int kt = k0; kt < kend; kt++) {
        const int buf = kt & 1;
        *(h8*)&Ks[buf][krow][kc0] = kreg[0];
        *(h8*)&Ks[buf][krow + 32][kc0] = kreg[1];
#pragma unroll
        for (int j = 0; j < 4; j++) {
            h4 t;
            t[0] = vreg[0][j]; t[1] = vreg[1][j]; t[2] = vreg[2][j]; t[3] = vreg[3][j];
            *(h4*)&Vt[buf][vp0 + j][vc0] = t;
        }
        if (kt + 1 < kend) {   // prefetch next K/V tiles into regs
            const _Float16* kp = kh + base + (size_t)((kt + 1) * 64) * 64;
            kreg[0] = *(const h8*)(kp + (size_t)krow * 64 + kc0);
            kreg[1] = *(const h8*)(kp + (size_t)(krow + 32) * 64 + kc0);
            const _Float16* vp = vh + base + (size_t)((kt + 1) * 64 + vc0) * 64 + vp0;
#pragma unroll
            for (int i = 0; i < 4; i++) vreg[i] = *(const h4*)(vp + (size_t)i * 64);
        }
        __syncthreads();

        const bool skip = (kt * 64) > (qbase + 31);   // wave fully above diagonal
        if (!skip) {
            // S^T = K Q^T : D[s=quad*4+reg][m=l16], per strip u; kf shared across strips
            f32x4 s[2][4];
#pragma unroll
            for (int nt = 0; nt < 4; nt++) {
                h8 kf0 = *(const h8*)&Ks[buf][nt * 16 + l16][quad * 8];
                h8 kf1 = *(const h8*)&Ks[buf][nt * 16 + l16][32 + quad * 8];
#pragma unroll
                for (int u = 0; u < 2; u++) {
                    f32x4 c = (f32x4){0.f, 0.f, 0.f, 0.f};
                    c = __builtin_amdgcn_mfma_f32_16x16x32_f16(kf0, qf[u][0], c, 0, 0, 0);
                    c = __builtin_amdgcn_mfma_f32_16x16x32_f16(kf1, qf[u][1], c, 0, 0, 0);
                    s[u][nt] = c;
                }
            }

            h4 pf[2][4];
#pragma unroll
            for (int u = 0; u < 2; u++) {
                const int qrow = qbase + u * 16 + l16;
                if (kt * 64 + 63 > qbase + u * 16) {   // causal mask needed
#pragma unroll
                    for (int nt = 0; nt < 4; nt++)
#pragma unroll
                        for (int reg = 0; reg < 4; reg++) {
                            int sg = kt * 64 + nt * 16 + quad * 4 + reg;
                            if (sg > qrow) s[u][nt][reg] = MASKV;
                        }
                }
                float mx = s[u][0][0];
#pragma unroll
                for (int nt = 0; nt < 4; nt++)
#pragma unroll
                    for (int reg = 0; reg < 4; reg++) mx = fmaxf(mx, s[u][nt][reg]);
                mx = fmaxf(mx, __shfl_xor(mx, 16));
                mx = fmaxf(mx, __shfl_xor(mx, 32));
                float mnew = fmaxf(m[u], mx);
                float alpha = EXP2(m[u] - mnew);
                m[u] = mnew;
                float rs = 0.f;
#pragma unroll
                for (int nt = 0; nt < 4; nt++) {
                    h4 ph;
#pragma unroll
                    for (int reg = 0; reg < 4; reg++) {
                        float p = EXP2(s[u][nt][reg] - mnew);
                        rs += p;
                        ph[reg] = (_Float16)p;
                    }
                    pf[u][nt] = ph;
                }
                rs += __shfl_xor(rs, 16);
                rs += __shfl_xor(rs, 32);
                l[u] = l[u] * alpha + rs;
#pragma unroll
                for (int pt = 0; pt < 4; pt++)
#pragma unroll
                    for (int reg = 0; reg < 4; reg++) o[u * 4 + pt][reg] *= alpha;
            }

            // O^T += V^T P^T ; vf shared across strips
#pragma unroll
            for (int pt = 0; pt < 4; pt++)
#pragma unroll
                for (int nt = 0; nt < 4; nt++) {
                    h4 vf = *(const h4*)&Vt[buf][pt * 16 + l16][nt * 16 + quad * 4];
                    o[pt]     = __builtin_amdgcn_mfma_f32_16x16x16f16(vf, pf[0][nt], o[pt], 0, 0, 0);
                    o[4 + pt] = __builtin_amdgcn_mfma_f32_16x16x16f16(vf, pf[1][nt], o[4 + pt], 0, 0, 0);
                }
        }
    }

    if (direct) {
#pragma unroll
        for (int u = 0; u < 2; u++) {
            float linv = 1.0f / l[u];
            int trow = qt2 * 128 + w * 32 + u * 16 + l16;
#pragma unroll
            for (int pt = 0; pt < 4; pt++)
#pragma unroll
                for (int reg = 0; reg < 4; reg++)
                    out[base + (size_t)trow * 64 + pt * 16 + quad * 4 + reg] =
                        o[u * 4 + pt][reg] * linv;
        }
    } else {
        // stage O^T -> LDS -> coalesced h8 stores
        __syncthreads();                       // all waves done reading Ks/Vt
        _Float16* St = &Ks[0][0][0];           // 128 x 72 halfs (exactly 9216)
#pragma unroll
        for (int u = 0; u < 2; u++) {
            int r = w * 32 + u * 16 + l16;
#pragma unroll
            for (int pt = 0; pt < 4; pt++) {
                h4 ph;
#pragma unroll
                for (int reg = 0; reg < 4; reg++) ph[reg] = (_Float16)o[u * 4 + pt][reg];
                *(h4*)&St[r * 72 + pt * 16 + quad * 4] = ph;
            }
            if (quad == 0) ml[(size_t)cid * 128 + r] = make_float2(m[u], l[u]);
        }
        __syncthreads();
        _Float16* op = Opart + (size_t)cid * 8192;   // [128][64] f16
        const int r = tid >> 1, c0 = (tid & 1) * 32;
#pragma unroll
        for (int j = 0; j < 4; j++)
            *(h8*)(op + r * 64 + c0 + 8 * j) = *(const h8*)&St[r * 72 + c0 + 8 * j];
    }
}

// ---------------- kernel 3: merge split-K partials; grid 1024 (16-row groups)
__global__ __launch_bounds__(256) void combine_kernel(
    const _Float16* __restrict__ Opart, const float2* __restrict__ ml,
    float* __restrict__ out, int lgC, int NC1)
{
    const int C = 1 << lgC;
    const int task = blockIdx.x;                  // b(2b) | tile(5b) | rg(3b)
    const int b = task >> 8, tile = (task >> 3) & 31, rg = task & 7;
    int pref = 0;
    for (int i = 0; i < tile; i++) pref += (2 * i + 2 + C - 1) >> lgC;
    const int cbase = b * NC1 + pref;
    const int nch = (2 * tile + 2 + C - 1) >> lgC;

    const int r = rg * 16 + (threadIdx.x >> 4);   // local row in [0,128)
    const int c0 = (threadIdx.x & 15) * 4;

    float M = MINIT;
    for (int i = 0; i < nch; i++) M = fmaxf(M, ml[(size_t)(cbase + i) * 128 + r].x);
    float L = 0.f, acc[4] = {0.f, 0.f, 0.f, 0.f};
    for (int i = 0; i < nch; i++) {
        float2 v = ml[(size_t)(cbase + i) * 128 + r];
        float sc = EXP2(v.x - M);
        L += sc * v.y;
        h4 x4 = *(const h4*)(Opart + (size_t)(cbase + i) * 8192 + (size_t)r * 64 + c0);
#pragma unroll
        for (int t = 0; t < 4; t++) acc[t] += sc * (float)x4[t];
    }
    float inv = 1.0f / L;
    float4 res = { acc[0]*inv, acc[1]*inv, acc[2]*inv, acc[3]*inv };
    *(float4*)(out + ((size_t)b * T_ + tile * 128 + r) * 64 + c0) = res;
}

extern "C" void kernel_launch(void* const* d_in, const int* in_sizes, int n_in,
                              void* d_out, int out_size, void* d_ws, size_t ws_size,
                              hipStream_t stream) {
    const float* x    = (const float*)d_in[0];
    const float* W    = (const float*)d_in[1];
    const float* bias = (const float*)d_in[2];
    float* out = (float*)d_out;
    char* ws = (char*)d_ws;
    _Float16* qh = (_Float16*)(ws);
    _Float16* kh = (_Float16*)(ws + (size_t)2 * 1024 * 1024);
    _Float16* vh = (_Float16*)(ws + (size_t)4 * 1024 * 1024);
    _Float16* Wt = (_Float16*)(ws + (size_t)6 * 1024 * 1024);
    const size_t pbase = (size_t)8 * 1024 * 1024;

    // smallest C whose f16 partials fit in ws (128-row tiles)
    int lgC = -1, nc1 = 32;
    for (int lg = 2; lg <= 6; lg++) {
        int C = 1 << lg, n1 = 0;
        for (int i = 0; i < 32; i++) n1 += (2 * i + 2 + C - 1) >> lg;
        size_t need = pbase + (size_t)4 * n1 * (8192 * 2 + 128 * 8);
        if (need <= ws_size) { lgC = lg; nc1 = n1; break; }
    }
    int direct = (lgC < 0) ? 1 : 0;
    if (direct) { lgC = 6; nc1 = 32; }
    _Float16* Opart = (_Float16*)(ws + pbase);
    float2*   mlp   = (float2*)(ws + pbase + (size_t)4 * nc1 * 8192 * 2);

    const int total = 4 * nc1;
    const int q8 = (total + 7) / 8;

    wt_kernel<<<64, 256, 0, stream>>>(W, Wt);
    proj_kernel<<<512, 256, 0, stream>>>(x, Wt, bias, qh, kh, vh);
    attn_kernel<<<8 * q8, 256, 0, stream>>>(qh, kh, vh, out, Opart, mlp,
                                            lgC, nc1, direct, q8, total);
    if (!direct)
        combine_kernel<<<1024, 256, 0, stream>>>(Opart, mlp, out, lgC, nc1);
}